// Round 3
// baseline (986.919 us; speedup 1.0000x reference)
//
#include <hip/hip_runtime.h>

#define NTOK 49
#define DIM 192
#define HEADS 6
#define NWIN 64
#define NBLK 4096

typedef unsigned short u16;
typedef short bf16x8 __attribute__((ext_vector_type(8)));
typedef float f32x4 __attribute__((ext_vector_type(4)));

// LDS byte offsets. Region 0 (xs) is reused for aout in the proj phase;
// q/k/vt region is reused for proj_w.
#define XS_OFF   0          // u16 [64][200] = 25600
#define Q_OFF    25600      // u16 [64][200]
#define K_OFF    51200      // u16 [64][200]
#define VT_OFF   76800      // u16 [192][72] = 27648
#define P_OFF    104448     // u16 [64][72]  = 9216
#define LDS_TOTAL 113664
#define W_OFF    25600      // u16 [192][200] = 76800 (fits in q+k+vt)
#define AOUT_OFF 0          // u16 [64][200]

#define QKVW_ELEMS (3 * DIM * DIM)   // 110592
#define PROJW_ELEMS (DIM * DIM)      // 36864

__device__ __forceinline__ float bf2f(u16 u) {
    union { unsigned int i; float f; } x; x.i = ((unsigned int)u) << 16; return x.f;
}
__device__ __forceinline__ u16 f2bf(float f) {
    union { float f; unsigned int u; } x; x.f = f;
    unsigned int u = x.u;
    u += 0x7fffu + ((u >> 16) & 1u);   // RNE
    return (u16)(u >> 16);
}

// fp32 -> bf16 weight pre-convert into workspace
extern "C" __global__ void __launch_bounds__(256)
convert_weights(const float* __restrict__ qkv_w, const float* __restrict__ proj_w,
                u16* __restrict__ ws) {
    int i = (blockIdx.x * 256 + threadIdx.x) * 4;
    if (i >= QKVW_ELEMS + PROJW_ELEMS) return;
    const float* s = (i < QKVW_ELEMS) ? (qkv_w + i) : (proj_w + (i - QKVW_ELEMS));
    float4 v = *(const float4*)s;
    ushort4 o;
    o.x = f2bf(v.x); o.y = f2bf(v.y); o.z = f2bf(v.z); o.w = f2bf(v.w);
    *(ushort4*)(ws + i) = o;
}

extern "C" __global__ void __launch_bounds__(256)
fused_win_attn(const float* __restrict__ x, const float* __restrict__ mask,
               const u16* __restrict__ wsq, const float* __restrict__ qkv_b,
               const u16* __restrict__ wsp, const float* __restrict__ proj_b,
               const float* __restrict__ rfreq, float* __restrict__ out)
{
    extern __shared__ __align__(16) char smem[];
    u16* xs  = (u16*)(smem + XS_OFF);
    u16* qs  = (u16*)(smem + Q_OFF);
    u16* ksm = (u16*)(smem + K_OFF);
    u16* vt  = (u16*)(smem + VT_OFF);
    u16* ps  = (u16*)(smem + P_OFF);
    u16* wl  = (u16*)(smem + W_OFF);
    u16* ao  = (u16*)(smem + AOUT_OFF);

    const int tid  = threadIdx.x;
    const int wave = tid >> 6;
    const int lane = tid & 63;
    const int ln   = lane & 15;
    const int quad = lane >> 4;
    const int blk  = blockIdx.x;
    const int widx = blk & (NWIN - 1);
    const float* xg = x + (long)blk * NTOK * DIM;

    const f32x4 fzero = {0.f, 0.f, 0.f, 0.f};

    // ---------- stage X [49][192] fp32 -> LDS bf16 [64][200], zero pad rows ----------
    for (int i = tid; i < NTOK * 48; i += 256) {
        int r = i / 48, c = (i % 48) * 4;
        float4 v = *(const float4*)(xg + r * DIM + c);
        ushort4 o;
        o.x = f2bf(v.x); o.y = f2bf(v.y); o.z = f2bf(v.z); o.w = f2bf(v.w);
        *(ushort4*)(xs + r * 200 + c) = o;
    }
    {
        ushort4 zz = {0, 0, 0, 0};
        for (int i = tid; i < 15 * 48; i += 256) {
            int r = 49 + i / 48, c = (i % 48) * 4;
            *(ushort4*)(xs + r * 200 + c) = zz;
        }
    }
    __syncthreads();

    // ---------- QKV GEMM: M=channel(576), N=token(64), K=192 ----------
    // A = qkv_w rows (channel-major, contiguous K); B = xs rows.
    const float scale = 0.17677669529663687f;  // 32^-0.5
    for (int jt = wave; jt < 36; jt += 4) {
        bf16x8 af[6];
        const u16* wr = wsq + (jt * 16 + ln) * DIM + quad * 8;
        #pragma unroll
        for (int kk = 0; kk < 6; kk++) af[kk] = *(const bf16x8*)(wr + kk * 32);
        f32x4 acc[4];
        #pragma unroll
        for (int nt = 0; nt < 4; nt++) acc[nt] = fzero;
        #pragma unroll
        for (int kk = 0; kk < 6; kk++) {
            #pragma unroll
            for (int nt = 0; nt < 4; nt++) {
                bf16x8 bx = *(const bf16x8*)(xs + (nt * 16 + ln) * 200 + kk * 32 + quad * 8);
                acc[nt] = __builtin_amdgcn_mfma_f32_16x16x32_bf16(af[kk], bx, acc[nt], 0, 0, 0);
            }
        }
        // epilogue: bias, scale (q), rope (q,k); write to q/k [tok][c] or vT [c][tok]
        int j0 = jt * 16 + quad * 4;        // channel of reg 0 (even)
        int qkvi = j0 / DIM;                // 0=q 1=k 2=v
        int c0 = j0 % DIM;
        int h  = c0 >> 5;
        int p0 = (c0 & 31) >> 1;            // rope pair idx for regs (0,1); (2,3)->p0+1
        float b0 = qkv_b[j0],   b1 = qkv_b[j0+1];
        float b2 = qkv_b[j0+2], b3 = qkv_b[j0+3];
        float fx0 = rfreq[h*16+p0],   fy0 = rfreq[96+h*16+p0];
        float fx1 = rfreq[h*16+p0+1], fy1 = rfreq[96+h*16+p0+1];
        #pragma unroll
        for (int nt = 0; nt < 4; nt++) {
            int t = nt * 16 + ln;           // token (col)
            float v0 = acc[nt][0] + b0;
            float v1 = acc[nt][1] + b1;
            float v2 = acc[nt][2] + b2;
            float v3 = acc[nt][3] + b3;
            if (qkvi < 2) {
                float tx = (float)(t % 7), ty = (float)(t / 7);
                float a0 = tx * fx0 + ty * fy0;
                float a1 = tx * fx1 + ty * fy1;
                float s0, c0s, s1, c1s;
                __sincosf(a0, &s0, &c0s);
                __sincosf(a1, &s1, &c1s);
                float r0 = v0 * c0s - v1 * s0;
                float i0 = v0 * s0  + v1 * c0s;
                float r1 = v2 * c1s - v3 * s1;
                float i1 = v2 * s1  + v3 * c1s;
                if (qkvi == 0) { r0 *= scale; i0 *= scale; r1 *= scale; i1 *= scale; }
                v0 = r0; v1 = i0; v2 = r1; v3 = i1;
            }
            if (qkvi == 2) {
                vt[(c0+0)*72 + t] = f2bf(v0);
                vt[(c0+1)*72 + t] = f2bf(v1);
                vt[(c0+2)*72 + t] = f2bf(v2);
                vt[(c0+3)*72 + t] = f2bf(v3);
            } else {
                u16* dst = (qkvi == 0 ? qs : ksm) + t * 200 + c0;
                dst[0] = f2bf(v0); dst[1] = f2bf(v1);
                dst[2] = f2bf(v2); dst[3] = f2bf(v3);
            }
        }
    }
    __syncthreads();

    // ---------- attention: per head, S=QK^T (K=32), softmax, O=PV ----------
    f32x4 oacc[12];
    for (int h = 0; h < HEADS; h++) {
        f32x4 s4[4];
        bf16x8 aq = *(const bf16x8*)(qs + (wave*16 + ln) * 200 + h*32 + quad*8);
        #pragma unroll
        for (int nt = 0; nt < 4; nt++) {
            bf16x8 bk = *(const bf16x8*)(ksm + (nt*16 + ln) * 200 + h*32 + quad*8);
            s4[nt] = __builtin_amdgcn_mfma_f32_16x16x32_bf16(aq, bk, fzero, 0, 0, 0);
        }
        // mask add; pad columns -> -1e30
        #pragma unroll
        for (int nt = 0; nt < 4; nt++) {
            int m = nt * 16 + ln;
            #pragma unroll
            for (int r = 0; r < 4; r++) {
                int n = wave*16 + quad*4 + r;
                if (m >= NTOK) s4[nt][r] = -1e30f;
                else if (n < NTOK) s4[nt][r] += mask[widx*(NTOK*NTOK) + n*NTOK + m];
            }
        }
        // rows live in (quad, reg); columns across nt and the 16 ln lanes
        float mx[4], sm[4], rs[4];
        #pragma unroll
        for (int r = 0; r < 4; r++) {
            float v = fmaxf(fmaxf(s4[0][r], s4[1][r]), fmaxf(s4[2][r], s4[3][r]));
            #pragma unroll
            for (int d = 1; d < 16; d <<= 1) v = fmaxf(v, __shfl_xor(v, d));
            mx[r] = v;
            sm[r] = 0.f;
        }
        #pragma unroll
        for (int nt = 0; nt < 4; nt++) {
            int m = nt * 16 + ln;
            #pragma unroll
            for (int r = 0; r < 4; r++) {
                float e = __expf(s4[nt][r] - mx[r]);   // pad cols: exp(-huge)=0
                sm[r] += e;
                ps[(wave*16 + quad*4 + r)*72 + m] = f2bf(e);
            }
        }
        #pragma unroll
        for (int r = 0; r < 4; r++) {
            float v = sm[r];
            #pragma unroll
            for (int d = 1; d < 16; d <<= 1) v += __shfl_xor(v, d);
            rs[r] = 1.0f / v;
        }
        __syncthreads();   // P, before PV reads

        f32x4 o0 = fzero, o1 = fzero;
        #pragma unroll
        for (int kk = 0; kk < 2; kk++) {
            bf16x8 ap  = *(const bf16x8*)(ps + (wave*16 + ln)*72 + kk*32 + quad*8);
            bf16x8 bv0 = *(const bf16x8*)(vt + (h*32 + ln)*72      + kk*32 + quad*8);
            bf16x8 bv1 = *(const bf16x8*)(vt + (h*32 + 16 + ln)*72 + kk*32 + quad*8);
            o0 = __builtin_amdgcn_mfma_f32_16x16x32_bf16(ap, bv0, o0, 0, 0, 0);
            o1 = __builtin_amdgcn_mfma_f32_16x16x32_bf16(ap, bv1, o1, 0, 0, 0);
        }
        // normalize: O rows (quad,reg) match rs rows exactly
        #pragma unroll
        for (int r = 0; r < 4; r++) { o0[r] *= rs[r]; o1[r] *= rs[r]; }
        oacc[2*h]   = o0;
        oacc[2*h+1] = o1;
        __syncthreads();   // before next head overwrites ps
    }

    // ---------- write attention out to LDS; stage proj_w ----------
    #pragma unroll
    for (int h = 0; h < HEADS; h++)
        #pragma unroll
        for (int dt = 0; dt < 2; dt++)
            #pragma unroll
            for (int r = 0; r < 4; r++)
                ao[(wave*16 + quad*4 + r)*200 + h*32 + dt*16 + ln] = f2bf(oacc[2*h+dt][r]);
    for (int c = tid; c < DIM * 24; c += 256) {
        int r = c / 24, col = (c % 24) * 8;
        *(bf16x8*)(wl + r * 200 + col) = *(const bf16x8*)(wsp + r * DIM + col);
    }
    __syncthreads();

    // ---------- proj: M=token(64), N=192, K=192 ----------
    bf16x8 aa[6];
    #pragma unroll
    for (int kk = 0; kk < 6; kk++)
        aa[kk] = *(const bf16x8*)(ao + (wave*16 + ln) * 200 + kk*32 + quad*8);
    float* og = out + (long)blk * NTOK * DIM;
    for (int nt = 0; nt < 12; nt++) {
        f32x4 p4 = fzero;
        #pragma unroll
        for (int kk = 0; kk < 6; kk++) {
            bf16x8 bw = *(const bf16x8*)(wl + (nt*16 + ln) * 200 + kk*32 + quad*8);
            p4 = __builtin_amdgcn_mfma_f32_16x16x32_bf16(aa[kk], bw, p4, 0, 0, 0);
        }
        int j = nt * 16 + ln;
        float bb = proj_b[j];
        #pragma unroll
        for (int r = 0; r < 4; r++) {
            int t = wave*16 + quad*4 + r;
            if (t < NTOK) og[t * DIM + j] = p4[r] + bb;
        }
    }
}

extern "C" void kernel_launch(void* const* d_in, const int* in_sizes, int n_in,
                              void* d_out, int out_size, void* d_ws, size_t ws_size,
                              hipStream_t stream) {
    (void)in_sizes; (void)n_in; (void)out_size; (void)ws_size;
    u16* ws = (u16*)d_ws;
    convert_weights<<<dim3((QKVW_ELEMS + PROJW_ELEMS) / 4 / 256 + 1), dim3(256), 0, stream>>>(
        (const float*)d_in[2], (const float*)d_in[4], ws);
    hipFuncSetAttribute(reinterpret_cast<const void*>(fused_win_attn),
                        hipFuncAttributeMaxDynamicSharedMemorySize, LDS_TOTAL);
    fused_win_attn<<<dim3(NBLK), dim3(256), LDS_TOTAL, stream>>>(
        (const float*)d_in[0], (const float*)d_in[1],
        ws, (const float*)d_in[3],
        ws + QKVW_ELEMS, (const float*)d_in[5],
        (const float*)d_in[6], (float*)d_out);
}

// Round 4
// 733.982 us; speedup vs baseline: 1.3446x; 1.3446x over previous
//
#include <hip/hip_runtime.h>

#define NTOK 49
#define DIM 192
#define HEADS 6
#define NWIN 64
#define NBLK 4096

typedef unsigned short u16;
typedef short bf16x8 __attribute__((ext_vector_type(8)));
typedef unsigned short u16x4 __attribute__((ext_vector_type(4)));
typedef unsigned short u16x8 __attribute__((ext_vector_type(8)));
typedef float f32x4 __attribute__((ext_vector_type(4)));

// LDS map (bytes):
//  [0,20000)       q rows 0..49, stride 200 u16   (reused as ao in proj phase)
//  [20000,40000)   k rows 0..49, stride 200 u16
//  [40000,49216)   ps [64][72] u16
//  [49216,76864)   vt [192][72] u16   (xs [64][200] u16 overlays this in stage/hoist)
//  [20000,70176)   outstage [64][196] f32 overlays k+ps+vt in the store phase
//  [76864,81764)   mask bf16 [49][50]
#define Q_OFF    0
#define K_OFF    20000
#define PS_OFF   40000
#define VT_OFF   49216
#define XS_OFF   49216
#define OS_OFF   20000
#define MK_OFF   76864
#define LDS_TOTAL 81764

#define QKVW_ELEMS (3 * DIM * DIM)   // 110592
#define PROJW_ELEMS (DIM * DIM)      // 36864

__device__ __forceinline__ float bf2f(u16 u) {
    union { unsigned int i; float f; } x; x.i = ((unsigned int)u) << 16; return x.f;
}
__device__ __forceinline__ u16 f2bf(float f) {
    union { float f; unsigned int u; } x; x.f = f;
    unsigned int u = x.u;
    u += 0x7fffu + ((u >> 16) & 1u);   // RNE
    return (u16)(u >> 16);
}

// fp32 -> bf16 weight pre-convert into workspace
extern "C" __global__ void __launch_bounds__(256)
convert_weights(const float* __restrict__ qkv_w, const float* __restrict__ proj_w,
                u16* __restrict__ ws) {
    int i = (blockIdx.x * 256 + threadIdx.x) * 4;
    if (i >= QKVW_ELEMS + PROJW_ELEMS) return;
    const float* s = (i < QKVW_ELEMS) ? (qkv_w + i) : (proj_w + (i - QKVW_ELEMS));
    float4 v = *(const float4*)s;
    ushort4 o;
    o.x = f2bf(v.x); o.y = f2bf(v.y); o.z = f2bf(v.z); o.w = f2bf(v.w);
    *(ushort4*)(ws + i) = o;
}

extern "C" __global__ void __launch_bounds__(256, 2)
fused_win_attn(const float* __restrict__ x, const float* __restrict__ mask,
               const u16* __restrict__ wsq, const float* __restrict__ qkv_b,
               const u16* __restrict__ wsp, const float* __restrict__ proj_b,
               const float* __restrict__ rfreq, float* __restrict__ out)
{
    extern __shared__ __align__(16) char smem[];
    u16* qsm = (u16*)(smem + Q_OFF);
    u16* ksm = (u16*)(smem + K_OFF);
    u16* ps  = (u16*)(smem + PS_OFF);
    u16* vt  = (u16*)(smem + VT_OFF);
    u16* xs  = (u16*)(smem + XS_OFF);
    float* os = (float*)(smem + OS_OFF);
    u16* ao  = (u16*)(smem + Q_OFF);
    u16* mk  = (u16*)(smem + MK_OFF);

    const int tid  = threadIdx.x;
    const int wave = tid >> 6;
    const int lane = tid & 63;
    const int ln   = lane & 15;
    const int quad = lane >> 4;
    const int blk  = blockIdx.x;
    const int widx = blk & (NWIN - 1);
    const float* xg = x + (long)blk * NTOK * DIM;

    const f32x4 fzero = {0.f, 0.f, 0.f, 0.f};

    // ============ phase 1: stage x -> xs (bf16), zero pads, stage mask ============
    for (int i = tid; i < NTOK * 48; i += 256) {
        int r = i / 48, c = (i % 48) * 4;
        float4 v = *(const float4*)(xg + r * DIM + c);
        u16x4 o = { f2bf(v.x), f2bf(v.y), f2bf(v.z), f2bf(v.w) };
        *(u16x4*)(xs + r * 200 + c) = o;
    }
    {
        u16x8 zz = {0,0,0,0,0,0,0,0};
        for (int i = tid; i < 15 * 25; i += 256) {       // xs rows 49..63 zero
            int r = 49 + i / 25, c = (i % 25) * 8;
            *(u16x8*)(xs + r * 200 + c) = zz;
        }
        if (tid < 50) {                                   // q row49, k row49 zero
            int c = (tid % 25) * 8;
            u16* base = (tid < 25) ? qsm : ksm;
            *(u16x8*)(base + 49 * 200 + c) = zz;
        }
    }
    for (int i = tid; i < NTOK * NTOK; i += 256) {        // mask -> LDS bf16
        int n = i / NTOK, m = i % NTOK;
        mk[n * 50 + m] = f2bf(mask[widx * (NTOK * NTOK) + i]);
    }
    __syncthreads();

    // ============ phase 2: hoist QKV B-frags (x tokens) into registers ============
    bf16x8 bfrag[6][4];
    #pragma unroll
    for (int kk = 0; kk < 6; kk++)
        #pragma unroll
        for (int nt = 0; nt < 4; nt++)
            bfrag[kk][nt] = *(const bf16x8*)(xs + (nt * 16 + ln) * 200 + kk * 32 + quad * 8);
    __syncthreads();   // xs region about to be overwritten by vt

    // ============ phase 3: QKV GEMM, M=channel(576), N=token(64), K=192 ============
    const float scale = 0.17677669529663687f;  // 32^-0.5
    for (int jt = wave; jt < 36; jt += 4) {
        bf16x8 af[6];
        const u16* wr = wsq + (jt * 16 + ln) * DIM + quad * 8;
        #pragma unroll
        for (int kk = 0; kk < 6; kk++) af[kk] = *(const bf16x8*)(wr + kk * 32);
        f32x4 acc[4];
        #pragma unroll
        for (int nt = 0; nt < 4; nt++) acc[nt] = fzero;
        #pragma unroll
        for (int kk = 0; kk < 6; kk++)
            #pragma unroll
            for (int nt = 0; nt < 4; nt++)
                acc[nt] = __builtin_amdgcn_mfma_f32_16x16x32_bf16(af[kk], bfrag[kk][nt], acc[nt], 0, 0, 0);

        int j0 = jt * 16 + quad * 4;        // channel of reg 0
        int qkvi = j0 / DIM;                // wave-uniform: 0=q 1=k 2=v
        int c0 = j0 % DIM;
        int h  = c0 >> 5;
        int p0 = (c0 & 31) >> 1;
        float b0 = qkv_b[j0],   b1 = qkv_b[j0+1];
        float b2 = qkv_b[j0+2], b3 = qkv_b[j0+3];
        float fx0 = rfreq[h*16+p0],   fy0 = rfreq[96+h*16+p0];
        float fx1 = rfreq[h*16+p0+1], fy1 = rfreq[96+h*16+p0+1];
        #pragma unroll
        for (int nt = 0; nt < 4; nt++) {
            int t = nt * 16 + ln;           // token
            float v0 = acc[nt][0] + b0;
            float v1 = acc[nt][1] + b1;
            float v2 = acc[nt][2] + b2;
            float v3 = acc[nt][3] + b3;
            if (qkvi < 2) {
                float tx = (float)(t % 7), ty = (float)(t / 7);
                float a0 = tx * fx0 + ty * fy0;
                float a1 = tx * fx1 + ty * fy1;
                float s0, c0s, s1, c1s;
                __sincosf(a0, &s0, &c0s);
                __sincosf(a1, &s1, &c1s);
                float r0 = v0 * c0s - v1 * s0;
                float i0 = v0 * s0  + v1 * c0s;
                float r1 = v2 * c1s - v3 * s1;
                float i1 = v2 * s1  + v3 * c1s;
                if (qkvi == 0) { r0 *= scale; i0 *= scale; r1 *= scale; i1 *= scale; }
                if (t < NTOK) {
                    u16x4 pk = { f2bf(r0), f2bf(i0), f2bf(r1), f2bf(i1) };
                    u16* dst = (qkvi == 0 ? qsm : ksm) + t * 200 + c0;
                    *(u16x4*)dst = pk;
                }
            } else {
                float w0 = (t < NTOK) ? v0 : 0.f;
                float w1 = (t < NTOK) ? v1 : 0.f;
                float w2 = (t < NTOK) ? v2 : 0.f;
                float w3 = (t < NTOK) ? v3 : 0.f;
                vt[(c0+0)*72 + t] = f2bf(w0);
                vt[(c0+1)*72 + t] = f2bf(w1);
                vt[(c0+2)*72 + t] = f2bf(w2);
                vt[(c0+3)*72 + t] = f2bf(w3);
            }
        }
    }
    __syncthreads();

    // ============ phase 4: attention (no barriers; ps rows are wave-private) ======
    f32x4 oacc[12];
    int qrow = wave * 16 + ln; if (qrow > NTOK) qrow = NTOK;   // pad tokens -> zero row 49
    for (int h = 0; h < HEADS; h++) {
        f32x4 s4[4];
        bf16x8 aq = *(const bf16x8*)(qsm + qrow * 200 + h * 32 + quad * 8);
        #pragma unroll
        for (int nt = 0; nt < 4; nt++) {
            int krow = nt * 16 + ln; if (krow > NTOK) krow = NTOK;
            bf16x8 bk = *(const bf16x8*)(ksm + krow * 200 + h * 32 + quad * 8);
            s4[nt] = __builtin_amdgcn_mfma_f32_16x16x32_bf16(aq, bk, fzero, 0, 0, 0);
        }
        #pragma unroll
        for (int nt = 0; nt < 4; nt++) {
            int m = nt * 16 + ln;
            #pragma unroll
            for (int r = 0; r < 4; r++) {
                int n = wave * 16 + quad * 4 + r;
                if (m >= NTOK) s4[nt][r] = -1e30f;
                else if (n < NTOK) s4[nt][r] += bf2f(mk[n * 50 + m]);
            }
        }
        float mx[4], sm[4], rs[4];
        #pragma unroll
        for (int r = 0; r < 4; r++) {
            float v = fmaxf(fmaxf(s4[0][r], s4[1][r]), fmaxf(s4[2][r], s4[3][r]));
            #pragma unroll
            for (int d = 1; d < 16; d <<= 1) v = fmaxf(v, __shfl_xor(v, d));
            mx[r] = v; sm[r] = 0.f;
        }
        #pragma unroll
        for (int nt = 0; nt < 4; nt++) {
            int m = nt * 16 + ln;
            #pragma unroll
            for (int r = 0; r < 4; r++) {
                float e = __expf(s4[nt][r] - mx[r]);
                sm[r] += e;
                ps[(wave * 16 + quad * 4 + r) * 72 + m] = f2bf(e);
            }
        }
        #pragma unroll
        for (int r = 0; r < 4; r++) {
            float v = sm[r];
            #pragma unroll
            for (int d = 1; d < 16; d <<= 1) v += __shfl_xor(v, d);
            rs[r] = 1.0f / v;
        }
        f32x4 o0 = fzero, o1 = fzero;
        #pragma unroll
        for (int kk = 0; kk < 2; kk++) {
            bf16x8 ap  = *(const bf16x8*)(ps + (wave * 16 + ln) * 72 + kk * 32 + quad * 8);
            bf16x8 bv0 = *(const bf16x8*)(vt + (h * 32 + ln) * 72      + kk * 32 + quad * 8);
            bf16x8 bv1 = *(const bf16x8*)(vt + (h * 32 + 16 + ln) * 72 + kk * 32 + quad * 8);
            o0 = __builtin_amdgcn_mfma_f32_16x16x32_bf16(ap, bv0, o0, 0, 0, 0);
            o1 = __builtin_amdgcn_mfma_f32_16x16x32_bf16(ap, bv1, o1, 0, 0, 0);
        }
        #pragma unroll
        for (int r = 0; r < 4; r++) { o0[r] *= rs[r]; o1[r] *= rs[r]; }
        oacc[2*h]   = o0;
        oacc[2*h+1] = o1;
    }

    // ============ phase 5: attention out -> ao (q region, wave-private rows) ======
    #pragma unroll
    for (int h = 0; h < HEADS; h++)
        #pragma unroll
        for (int dt = 0; dt < 2; dt++)
            #pragma unroll
            for (int r = 0; r < 4; r++) {
                int t = wave * 16 + quad * 4 + r;
                if (t < NTOK)
                    ao[t * 200 + h * 32 + dt * 16 + ln] = f2bf(oacc[2*h+dt][r]);
                else if (t == NTOK)
                    ao[t * 200 + h * 32 + dt * 16 + ln] = 0;   // zero clamp row
            }
    __syncthreads();   // all waves done reading k/ps/vt before outstage overlays them

    // ============ phase 6: proj GEMM, B-frags straight from global (L2-hot) =======
    bf16x8 aa[6];
    int arow = wave * 16 + ln; if (arow > NTOK) arow = NTOK;
    #pragma unroll
    for (int kk = 0; kk < 6; kk++)
        aa[kk] = *(const bf16x8*)(ao + arow * 200 + kk * 32 + quad * 8);
    for (int nt = 0; nt < 12; nt++) {
        const u16* wp = wsp + (nt * 16 + ln) * DIM + quad * 8;
        f32x4 p4 = fzero;
        #pragma unroll
        for (int kk = 0; kk < 6; kk++) {
            bf16x8 bw = *(const bf16x8*)(wp + kk * 32);
            p4 = __builtin_amdgcn_mfma_f32_16x16x32_bf16(aa[kk], bw, p4, 0, 0, 0);
        }
        float bb = proj_b[nt * 16 + ln];
        #pragma unroll
        for (int r = 0; r < 4; r++) {
            int t = wave * 16 + quad * 4 + r;
            os[t * 196 + nt * 16 + ln] = p4[r] + bb;
        }
    }
    __syncthreads();

    // ============ phase 7: coalesced co-op store ============
    float* og = out + (long)blk * NTOK * DIM;
    for (int i = tid; i < NTOK * 48; i += 256) {
        int r = i / 48, c = (i % 48) * 4;
        *(float4*)(og + r * DIM + c) = *(const float4*)(os + r * 196 + c);
    }
}

extern "C" void kernel_launch(void* const* d_in, const int* in_sizes, int n_in,
                              void* d_out, int out_size, void* d_ws, size_t ws_size,
                              hipStream_t stream) {
    (void)in_sizes; (void)n_in; (void)out_size; (void)ws_size;
    u16* ws = (u16*)d_ws;
    convert_weights<<<dim3((QKVW_ELEMS + PROJW_ELEMS) / 4 / 256 + 1), dim3(256), 0, stream>>>(
        (const float*)d_in[2], (const float*)d_in[4], ws);
    hipFuncSetAttribute(reinterpret_cast<const void*>(fused_win_attn),
                        hipFuncAttributeMaxDynamicSharedMemorySize, LDS_TOTAL);
    fused_win_attn<<<dim3(NBLK), dim3(256), LDS_TOTAL, stream>>>(
        (const float*)d_in[0], (const float*)d_in[1],
        ws, (const float*)d_in[3],
        ws + QKVW_ELEMS, (const float*)d_in[5],
        (const float*)d_in[6], (float*)d_out);
}

// Round 5
// 618.868 us; speedup vs baseline: 1.5947x; 1.1860x over previous
//
#include <hip/hip_runtime.h>

#define NTOK 49
#define DIM 192
#define HEADS 6
#define NWIN 64
#define NBLK 4096

typedef unsigned short u16;
typedef short bf16x8 __attribute__((ext_vector_type(8)));
typedef unsigned short u16x4 __attribute__((ext_vector_type(4)));
typedef unsigned short u16x8 __attribute__((ext_vector_type(8)));
typedef float f32x4 __attribute__((ext_vector_type(4)));

// LDS map (bytes):
//  [0,20000)       q rows 0..49, stride 200 u16   (o written back in-place per head)
//  [20000,40000)   k rows 0..49, stride 200 u16
//  [40000,49216)   ps [64][72] u16
//  [49216,76864)   vt [192][72] u16   (xs [64][200] u16 overlays this in stage/hoist)
//  [20000,70176)   outstage [64][196] f32 overlays k+ps+vt in the store phase
//  [76864,81764)   mask bf16 [49][50]
#define Q_OFF    0
#define K_OFF    20000
#define PS_OFF   40000
#define VT_OFF   49216
#define XS_OFF   49216
#define OS_OFF   20000
#define MK_OFF   76864
#define LDS_TOTAL 81764

#define QKVW_ELEMS (3 * DIM * DIM)   // 110592
#define PROJW_ELEMS (DIM * DIM)      // 36864

__device__ __forceinline__ float bf2f(u16 u) {
    union { unsigned int i; float f; } x; x.i = ((unsigned int)u) << 16; return x.f;
}
__device__ __forceinline__ u16 f2bf(float f) {
    union { float f; unsigned int u; } x; x.f = f;
    unsigned int u = x.u;
    u += 0x7fffu + ((u >> 16) & 1u);   // RNE
    return (u16)(u >> 16);
}

// fp32 -> bf16 weight pre-convert into workspace
extern "C" __global__ void __launch_bounds__(256)
convert_weights(const float* __restrict__ qkv_w, const float* __restrict__ proj_w,
                u16* __restrict__ ws) {
    int i = (blockIdx.x * 256 + threadIdx.x) * 4;
    if (i >= QKVW_ELEMS + PROJW_ELEMS) return;
    const float* s = (i < QKVW_ELEMS) ? (qkv_w + i) : (proj_w + (i - QKVW_ELEMS));
    float4 v = *(const float4*)s;
    ushort4 o;
    o.x = f2bf(v.x); o.y = f2bf(v.y); o.z = f2bf(v.z); o.w = f2bf(v.w);
    *(ushort4*)(ws + i) = o;
}

extern "C" __global__ void __launch_bounds__(256, 2)
fused_win_attn(const float* __restrict__ x, const float* __restrict__ mask,
               const u16* __restrict__ wsq, const float* __restrict__ qkv_b,
               const u16* __restrict__ wsp, const float* __restrict__ proj_b,
               const float* __restrict__ rfreq, float* __restrict__ out)
{
    extern __shared__ __align__(16) char smem[];
    u16* qsm = (u16*)(smem + Q_OFF);
    u16* ksm = (u16*)(smem + K_OFF);
    u16* ps  = (u16*)(smem + PS_OFF);
    u16* vt  = (u16*)(smem + VT_OFF);
    u16* xs  = (u16*)(smem + XS_OFF);
    float* os = (float*)(smem + OS_OFF);
    u16* ao  = (u16*)(smem + Q_OFF);
    u16* mk  = (u16*)(smem + MK_OFF);

    const int tid  = threadIdx.x;
    const int wave = tid >> 6;
    const int lane = tid & 63;
    const int ln   = lane & 15;
    const int quad = lane >> 4;
    const int blk  = blockIdx.x;
    const int widx = blk & (NWIN - 1);
    const float* xg = x + (long)blk * NTOK * DIM;

    const f32x4 fzero = {0.f, 0.f, 0.f, 0.f};

    // ============ phase 1: stage x -> xs (bf16), zero pads, stage mask ============
    for (int i = tid; i < NTOK * 48; i += 256) {
        int r = i / 48, c = (i % 48) * 4;
        float4 v = *(const float4*)(xg + r * DIM + c);
        u16x4 o = { f2bf(v.x), f2bf(v.y), f2bf(v.z), f2bf(v.w) };
        *(u16x4*)(xs + r * 200 + c) = o;
    }
    {
        u16x8 zz = {0,0,0,0,0,0,0,0};
        for (int i = tid; i < 15 * 25; i += 256) {       // xs rows 49..63 zero
            int r = 49 + i / 25, c = (i % 25) * 8;
            *(u16x8*)(xs + r * 200 + c) = zz;
        }
        if (tid < 50) {                                   // q row49, k row49 zero
            int c = (tid % 25) * 8;
            u16* base = (tid < 25) ? qsm : ksm;
            *(u16x8*)(base + 49 * 200 + c) = zz;
        }
    }
    for (int i = tid; i < NTOK * NTOK; i += 256) {        // mask -> LDS bf16
        int n = i / NTOK, m = i % NTOK;
        mk[n * 50 + m] = f2bf(mask[widx * (NTOK * NTOK) + i]);
    }
    __syncthreads();

    // ============ phase 2: hoist QKV B-frags (x tokens) into registers ============
    bf16x8 bfrag[6][4];
    #pragma unroll
    for (int kk = 0; kk < 6; kk++)
        #pragma unroll
        for (int nt = 0; nt < 4; nt++)
            bfrag[kk][nt] = *(const bf16x8*)(xs + (nt * 16 + ln) * 200 + kk * 32 + quad * 8);
    __syncthreads();   // xs region about to be overwritten by vt

    // ============ phase 3: QKV GEMM, M=channel(576), N=token(64), K=192 ============
    const float scale = 0.17677669529663687f;  // 32^-0.5
    for (int jt = wave; jt < 36; jt += 4) {
        bf16x8 af[6];
        const u16* wr = wsq + (jt * 16 + ln) * DIM + quad * 8;
        #pragma unroll
        for (int kk = 0; kk < 6; kk++) af[kk] = *(const bf16x8*)(wr + kk * 32);
        f32x4 acc[4];
        #pragma unroll
        for (int nt = 0; nt < 4; nt++) acc[nt] = fzero;
        #pragma unroll
        for (int kk = 0; kk < 6; kk++)
            #pragma unroll
            for (int nt = 0; nt < 4; nt++)
                acc[nt] = __builtin_amdgcn_mfma_f32_16x16x32_bf16(af[kk], bfrag[kk][nt], acc[nt], 0, 0, 0);

        int j0 = jt * 16 + quad * 4;        // channel of reg 0
        int qkvi = j0 / DIM;                // wave-uniform: 0=q 1=k 2=v
        int c0 = j0 % DIM;
        int h  = c0 >> 5;
        int p0 = (c0 & 31) >> 1;
        float b0 = qkv_b[j0],   b1 = qkv_b[j0+1];
        float b2 = qkv_b[j0+2], b3 = qkv_b[j0+3];
        float fx0 = rfreq[h*16+p0],   fy0 = rfreq[96+h*16+p0];
        float fx1 = rfreq[h*16+p0+1], fy1 = rfreq[96+h*16+p0+1];
        #pragma unroll
        for (int nt = 0; nt < 4; nt++) {
            int t = nt * 16 + ln;           // token
            float v0 = acc[nt][0] + b0;
            float v1 = acc[nt][1] + b1;
            float v2 = acc[nt][2] + b2;
            float v3 = acc[nt][3] + b3;
            if (qkvi < 2) {
                float tx = (float)(t % 7), ty = (float)(t / 7);
                float a0 = tx * fx0 + ty * fy0;
                float a1 = tx * fx1 + ty * fy1;
                float s0, c0s, s1, c1s;
                __sincosf(a0, &s0, &c0s);
                __sincosf(a1, &s1, &c1s);
                float r0 = v0 * c0s - v1 * s0;
                float i0 = v0 * s0  + v1 * c0s;
                float r1 = v2 * c1s - v3 * s1;
                float i1 = v2 * s1  + v3 * c1s;
                if (qkvi == 0) { r0 *= scale; i0 *= scale; r1 *= scale; i1 *= scale; }
                if (t < NTOK) {
                    u16x4 pk = { f2bf(r0), f2bf(i0), f2bf(r1), f2bf(i1) };
                    u16* dst = (qkvi == 0 ? qsm : ksm) + t * 200 + c0;
                    *(u16x4*)dst = pk;
                }
            } else {
                float w0 = (t < NTOK) ? v0 : 0.f;
                float w1 = (t < NTOK) ? v1 : 0.f;
                float w2 = (t < NTOK) ? v2 : 0.f;
                float w3 = (t < NTOK) ? v3 : 0.f;
                vt[(c0+0)*72 + t] = f2bf(w0);
                vt[(c0+1)*72 + t] = f2bf(w1);
                vt[(c0+2)*72 + t] = f2bf(w2);
                vt[(c0+3)*72 + t] = f2bf(w3);
            }
        }
    }
    __syncthreads();

    // ============ phase 4: attention; o written straight into ao (q region) =======
    // ps/ao rows are wave-private; later heads read q at strictly higher channels
    // than any earlier head's o-write, so no barriers inside this loop.
    int qrow = wave * 16 + ln; if (qrow > NTOK) qrow = NTOK;   // pad tokens -> zero row 49
    for (int h = 0; h < HEADS; h++) {
        f32x4 s4[4];
        bf16x8 aq = *(const bf16x8*)(qsm + qrow * 200 + h * 32 + quad * 8);
        #pragma unroll
        for (int nt = 0; nt < 4; nt++) {
            int krow = nt * 16 + ln; if (krow > NTOK) krow = NTOK;
            bf16x8 bk = *(const bf16x8*)(ksm + krow * 200 + h * 32 + quad * 8);
            s4[nt] = __builtin_amdgcn_mfma_f32_16x16x32_bf16(aq, bk, fzero, 0, 0, 0);
        }
        #pragma unroll
        for (int nt = 0; nt < 4; nt++) {
            int m = nt * 16 + ln;
            #pragma unroll
            for (int r = 0; r < 4; r++) {
                int n = wave * 16 + quad * 4 + r;
                if (m >= NTOK) s4[nt][r] = -1e30f;
                else if (n < NTOK) s4[nt][r] += bf2f(mk[n * 50 + m]);
            }
        }
        float mx[4], sm[4], rs[4];
        #pragma unroll
        for (int r = 0; r < 4; r++) {
            float v = fmaxf(fmaxf(s4[0][r], s4[1][r]), fmaxf(s4[2][r], s4[3][r]));
            #pragma unroll
            for (int d = 1; d < 16; d <<= 1) v = fmaxf(v, __shfl_xor(v, d));
            mx[r] = v; sm[r] = 0.f;
        }
        #pragma unroll
        for (int nt = 0; nt < 4; nt++) {
            int m = nt * 16 + ln;
            #pragma unroll
            for (int r = 0; r < 4; r++) {
                float e = __expf(s4[nt][r] - mx[r]);
                sm[r] += e;
                ps[(wave * 16 + quad * 4 + r) * 72 + m] = f2bf(e);
            }
        }
        #pragma unroll
        for (int r = 0; r < 4; r++) {
            float v = sm[r];
            #pragma unroll
            for (int d = 1; d < 16; d <<= 1) v += __shfl_xor(v, d);
            rs[r] = 1.0f / v;
        }
        f32x4 o0 = fzero, o1 = fzero;
        #pragma unroll
        for (int kk = 0; kk < 2; kk++) {
            bf16x8 ap  = *(const bf16x8*)(ps + (wave * 16 + ln) * 72 + kk * 32 + quad * 8);
            bf16x8 bv0 = *(const bf16x8*)(vt + (h * 32 + ln) * 72      + kk * 32 + quad * 8);
            bf16x8 bv1 = *(const bf16x8*)(vt + (h * 32 + 16 + ln) * 72 + kk * 32 + quad * 8);
            o0 = __builtin_amdgcn_mfma_f32_16x16x32_bf16(ap, bv0, o0, 0, 0, 0);
            o1 = __builtin_amdgcn_mfma_f32_16x16x32_bf16(ap, bv1, o1, 0, 0, 0);
        }
        // scale + write o for this head directly into ao (no register array, no scratch)
        #pragma unroll
        for (int r = 0; r < 4; r++) {
            int t = wave * 16 + quad * 4 + r;
            if (t < NTOK) {
                ao[t * 200 + h * 32 + ln]      = f2bf(o0[r] * rs[r]);
                ao[t * 200 + h * 32 + 16 + ln] = f2bf(o1[r] * rs[r]);
            }
        }
    }
    __syncthreads();   // all waves done with k/ps/vt before outstage overlays them

    // ============ phase 5: proj GEMM, B-frags straight from global (L2-hot) =======
    bf16x8 aa[6];
    int arow = wave * 16 + ln; if (arow > NTOK) arow = NTOK;
    #pragma unroll
    for (int kk = 0; kk < 6; kk++)
        aa[kk] = *(const bf16x8*)(ao + arow * 200 + kk * 32 + quad * 8);
    for (int nt = 0; nt < 12; nt++) {
        const u16* wp = wsp + (nt * 16 + ln) * DIM + quad * 8;
        f32x4 p4 = fzero;
        #pragma unroll
        for (int kk = 0; kk < 6; kk++) {
            bf16x8 bw = *(const bf16x8*)(wp + kk * 32);
            p4 = __builtin_amdgcn_mfma_f32_16x16x32_bf16(aa[kk], bw, p4, 0, 0, 0);
        }
        float bb = proj_b[nt * 16 + ln];
        #pragma unroll
        for (int r = 0; r < 4; r++) {
            int t = wave * 16 + quad * 4 + r;
            os[t * 196 + nt * 16 + ln] = p4[r] + bb;
        }
    }
    __syncthreads();

    // ============ phase 6: coalesced co-op store ============
    float* og = out + (long)blk * NTOK * DIM;
    for (int i = tid; i < NTOK * 48; i += 256) {
        int r = i / 48, c = (i % 48) * 4;
        *(float4*)(og + r * DIM + c) = *(const float4*)(os + r * 196 + c);
    }
}

extern "C" void kernel_launch(void* const* d_in, const int* in_sizes, int n_in,
                              void* d_out, int out_size, void* d_ws, size_t ws_size,
                              hipStream_t stream) {
    (void)in_sizes; (void)n_in; (void)out_size; (void)ws_size;
    u16* ws = (u16*)d_ws;
    convert_weights<<<dim3((QKVW_ELEMS + PROJW_ELEMS) / 4 / 256 + 1), dim3(256), 0, stream>>>(
        (const float*)d_in[2], (const float*)d_in[4], ws);
    hipFuncSetAttribute(reinterpret_cast<const void*>(fused_win_attn),
                        hipFuncAttributeMaxDynamicSharedMemorySize, LDS_TOTAL);
    fused_win_attn<<<dim3(NBLK), dim3(256), LDS_TOTAL, stream>>>(
        (const float*)d_in[0], (const float*)d_in[1],
        ws, (const float*)d_in[3],
        ws + QKVW_ELEMS, (const float*)d_in[5],
        (const float*)d_in[6], (float*)d_out);
}